// Round 13
// baseline (84.648 us; speedup 1.0000x reference)
//
#include <hip/hip_runtime.h>
#include <hip/hip_bf16.h>
#include <math.h>

// Shapes (fixed): B=4, S=2048, D=256, H=8, DH=32, DFF=1024
#define S_LEN 2048
#define D_MODEL 256
#define N_HEADS 8
#define HEAD_DIM 32
#define D_FF 1024
#define ROWS_TOTAL 8192  // B*S

typedef __attribute__((ext_vector_type(8))) short short8;
typedef __attribute__((ext_vector_type(4))) float f32x4;

__device__ inline ushort f2bf(float f) {
    unsigned u = __builtin_bit_cast(unsigned, f);
    unsigned r = (u + 0x7fffu + ((u >> 16) & 1u)) >> 16;
    return (ushort)r;
}

__device__ inline float bf2f(ushort u) {
    return __builtin_bit_cast(float, ((unsigned)u) << 16);
}

// packed f32x2 -> bf16x2 via HW instruction (RTNE)
__device__ inline unsigned cvtpk(float a, float b) {
    unsigned r;
    asm("v_cvt_pk_bf16_f32 %0, %1, %2" : "=v"(r) : "v"(a), "v"(b));
    return r;
}

// ---------------- prep: weights -> frag-major bf16 tiles + LN1 ----------------
// Frag-major: element (n,k) of W[N][K] -> tile t=(k>>5)*(N>>4)+(n>>4), in-tile
// ushort idx ((k>>3)&3)*128 + (n&15)*8 + (k&7). A lane (l15,hi) reading
// tile*512 + lane*8 gets W[tn*16+l15][tk*32+hi*8+j] = exact MFMA A/B fragment.
__device__ inline void cvt_frag(const float* __restrict__ src, ushort* __restrict__ dst,
                                int off, int kshift, int NT) {
    float4 v = ((const float4*)src)[off];
    int n = off >> kshift;
    int k = (off & ((1 << kshift) - 1)) << 2;
    int idx = (((k >> 5) * NT + (n >> 4)) << 9) + (((k >> 3) & 3) << 7) + ((n & 15) << 3) + (k & 7);
    ushort4 u = {f2bf(v.x), f2bf(v.y), f2bf(v.z), f2bf(v.w)};
    *(ushort4*)(dst + idx) = u;
}

__global__ __launch_bounds__(256) void prep_kernel(
    const float* __restrict__ w0, const float* __restrict__ w1,
    const float* __restrict__ w2, const float* __restrict__ w3,
    ushort* __restrict__ o0, ushort* __restrict__ o1,
    ushort* __restrict__ o2, ushort* __restrict__ o3,
    const float* __restrict__ x, const float* __restrict__ lnw,
    const float* __restrict__ lnb, ushort* __restrict__ xnb) {
    int blk = blockIdx.x;
    if (blk < 768) {
        int i = blk * 256 + threadIdx.x;
        if (i < 49152)       cvt_frag(w0, o0, i, 6, 48);           // in_w 768x256
        else if (i < 65536)  cvt_frag(w1, o1, i - 49152, 6, 16);   // out_w 256x256
        else if (i < 131072) cvt_frag(w2, o2, i - 65536, 6, 64);   // ff1 1024x256
        else                 cvt_frag(w3, o3, i - 131072, 8, 16);  // ff2 256x1024
    } else {
        int wid = threadIdx.x >> 6, lane = threadIdx.x & 63;
        int row = (blk - 768) * 4 + wid;
        float4 v = ((const float4*)(x + (size_t)row * D_MODEL))[lane];
        float4 wv = ((const float4*)lnw)[lane];
        float4 bv = ((const float4*)lnb)[lane];
        float s = v.x + v.y + v.z + v.w;
        float s2 = v.x * v.x + v.y * v.y + v.z * v.z + v.w * v.w;
        #pragma unroll
        for (int off = 1; off < 64; off <<= 1) {
            s  += __shfl_xor(s, off);
            s2 += __shfl_xor(s2, off);
        }
        float mu = s * (1.0f / D_MODEL);
        float var = s2 * (1.0f / D_MODEL) - mu * mu;
        float rstd = rsqrtf(var + 1e-5f);
        ushort4 o = {f2bf((v.x - mu) * rstd * wv.x + bv.x), f2bf((v.y - mu) * rstd * wv.y + bv.y),
                     f2bf((v.z - mu) * rstd * wv.z + bv.z), f2bf((v.w - mu) * rstd * wv.w + bv.w)};
        ((ushort4*)(xnb + (size_t)row * D_MODEL))[lane] = o;
    }
}

// ---------------- QKV GEMM: A staged once (K=256), B direct frag-major ----------------
// BM=64, BN=128, grid (128, 6). 4 waves 2x2: wave tile 32x64 (MR=2, NR=4).
__global__ __launch_bounds__(256) void gemm_qkv(
    const ushort* __restrict__ A,      // xnb, M x 256
    const ushort* __restrict__ Wt,     // in_w frag-major, NT=48
    const float* __restrict__ bias,
    ushort* __restrict__ qout, ushort* __restrict__ kout, ushort* __restrict__ vout) {
    __shared__ ushort As[64 * 256];
    const int tid = threadIdx.x;
    const int lane = tid & 63, wid = tid >> 6;
    const int l15 = lane & 15, hi = lane >> 4;
    const int wr = wid >> 1, wc = wid & 1;
    const int row0 = blockIdx.x * 64, col0 = blockIdx.y * 128;

    // stage A rows (once)
    #pragma unroll
    for (int t = 0; t < 8; t++) {
        int c = tid + t * 256;
        int r = c >> 5, cb = (c & 31) * 16;
        short8 va = *(const short8*)(A + (size_t)(row0 + r) * 256 + (c & 31) * 8);
        *(short8*)((char*)As + r * 512 + (cb ^ ((r & 7) << 4))) = va;
    }
    __syncthreads();

    f32x4 acc[2][4];
    #pragma unroll
    for (int m = 0; m < 2; m++)
        #pragma unroll
        for (int n = 0; n < 4; n++) acc[m][n] = (f32x4){0.f, 0.f, 0.f, 0.f};

    const int tn0 = (col0 >> 4) + wc * 4;
    #pragma unroll
    for (int tk = 0; tk < 8; tk++) {
        short8 af[2], bfr[4];
        #pragma unroll
        for (int m = 0; m < 2; m++) {
            int r = wr * 32 + m * 16 + l15;
            af[m] = *(const short8*)((char*)As + r * 512 + ((tk * 64 + hi * 16) ^ ((r & 7) << 4)));
        }
        #pragma unroll
        for (int n = 0; n < 4; n++)
            bfr[n] = *(const short8*)(Wt + (((size_t)tk * 48 + tn0 + n) << 9) + lane * 8);
        #pragma unroll
        for (int m = 0; m < 2; m++)
            #pragma unroll
            for (int n = 0; n < 4; n++)
                acc[m][n] = __builtin_amdgcn_mfma_f32_16x16x32_bf16(af[m], bfr[n], acc[m][n], 0, 0, 0);
    }

    #pragma unroll
    for (int m = 0; m < 2; m++) {
        #pragma unroll
        for (int n = 0; n < 4; n++) {
            #pragma unroll
            for (int r = 0; r < 4; r++) {
                int row = row0 + wr * 32 + m * 16 + hi * 4 + r;
                int col = col0 + wc * 64 + n * 16 + l15;
                float val = acc[m][n][r] + bias[col];
                int part = col >> 8;
                int d_o = col & 255;
                int hh = d_o >> 5, dh = d_o & 31;
                int bbb = row >> 11, s = row & 2047;
                size_t bhi = (size_t)bbb * N_HEADS + hh;
                if (part == 0) {
                    qout[(bhi * S_LEN + s) * HEAD_DIM + dh] = f2bf(val * 0.2550347137f);  // log2e/sqrt(32)
                } else {
                    int tt = s >> 6, k = s & 63;
                    size_t tb = (bhi * 32 + tt) * 2048;
                    if (part == 1)
                        kout[tb + (dh >> 3) * 512 + k * 8 + (dh & 7)] = f2bf(val);
                    else
                        vout[tb + ((size_t)((k >> 5) * 4 + ((k >> 3) & 3))) * 256 + dh * 8 + (k & 7)] = f2bf(val);
                }
            }
        }
    }
}

// ---------------- fused out-proj + residual + LN2 (A staged once, B direct) ----------
// BM=16, full N=256. Grid 512. Wave wid owns cols wid*64..+63 (4 frags).
__global__ __launch_bounds__(256) void gemm_opln(
    const ushort* __restrict__ A,      // ctx bf16, M x 256
    const ushort* __restrict__ Wt,     // out_w frag-major, NT=16
    const float* __restrict__ bias,
    const float* __restrict__ residf,  // x fp32
    const float* __restrict__ lnw, const float* __restrict__ lnb,
    ushort* __restrict__ xnb, ushort* __restrict__ x1b) {
    __shared__ ushort As[16 * 256];
    __shared__ float red[4][16][2];
    const int tid = threadIdx.x;
    const int lane = tid & 63, wid = tid >> 6;
    const int l15 = lane & 15, hi = lane >> 4;
    const int row0 = blockIdx.x * 16;

    #pragma unroll
    for (int t = 0; t < 2; t++) {
        int c = tid + t * 256;
        int r = c >> 5, cb = (c & 31) * 16;
        short8 va = *(const short8*)(A + (size_t)(row0 + r) * 256 + (c & 31) * 8);
        *(short8*)((char*)As + r * 512 + (cb ^ ((r & 7) << 4))) = va;
    }
    __syncthreads();

    f32x4 acc[4];
    #pragma unroll
    for (int n = 0; n < 4; n++) acc[n] = (f32x4){0.f, 0.f, 0.f, 0.f};

    #pragma unroll
    for (int tk = 0; tk < 8; tk++) {
        short8 af = *(const short8*)((char*)As + l15 * 512 + ((tk * 64 + hi * 16) ^ ((l15 & 7) << 4)));
        #pragma unroll
        for (int n = 0; n < 4; n++) {
            short8 bfr = *(const short8*)(Wt + (((size_t)tk * 16 + wid * 4 + n) << 9) + lane * 8);
            acc[n] = __builtin_amdgcn_mfma_f32_16x16x32_bf16(af, bfr, acc[n], 0, 0, 0);
        }
    }

    float x1v[4][4];
    float s1[4], s2[4];
    #pragma unroll
    for (int r = 0; r < 4; r++) { s1[r] = 0.f; s2[r] = 0.f; }
    #pragma unroll
    for (int n = 0; n < 4; n++) {
        #pragma unroll
        for (int r = 0; r < 4; r++) {
            int row = row0 + hi * 4 + r;
            int col = wid * 64 + n * 16 + l15;
            float v = acc[n][r] + bias[col] + residf[(size_t)row * 256 + col];
            x1v[n][r] = v;
            s1[r] += v;
            s2[r] += v * v;
        }
    }
    #pragma unroll
    for (int r = 0; r < 4; r++) {
        #pragma unroll
        for (int off = 1; off < 16; off <<= 1) {
            s1[r] += __shfl_xor(s1[r], off);
            s2[r] += __shfl_xor(s2[r], off);
        }
    }
    if (l15 == 0) {
        #pragma unroll
        for (int r = 0; r < 4; r++) {
            red[wid][hi * 4 + r][0] = s1[r];
            red[wid][hi * 4 + r][1] = s2[r];
        }
    }
    __syncthreads();
    #pragma unroll
    for (int r = 0; r < 4; r++) {
        int rl = hi * 4 + r;
        float a1 = red[0][rl][0] + red[1][rl][0] + red[2][rl][0] + red[3][rl][0];
        float a2 = red[0][rl][1] + red[1][rl][1] + red[2][rl][1] + red[3][rl][1];
        float mu = a1 * (1.0f / 256.f);
        float var = a2 * (1.0f / 256.f) - mu * mu;
        float rstd = rsqrtf(var + 1e-5f);
        size_t row = row0 + rl;
        #pragma unroll
        for (int n = 0; n < 4; n++) {
            int col = wid * 64 + n * 16 + l15;
            float v = x1v[n][r];
            xnb[row * 256 + col] = f2bf((v - mu) * rstd * lnw[col] + lnb[col]);
            x1b[row * 256 + col] = f2bf(v);
        }
    }
}

// ---------------- fused FFN: GELU(xn @ ff1^T + b1) @ ff2^T + b2 + x1 -> out ----------
// BM=16 rows/block, grid 512. Per 128-col h-chunk: FF1 via mfma(ff1_frag, x_frag)
// (swapped -> lane holds h[xrow=l15][ffcol]), pack via cvtpk -> Hs group-major,
// FF2 via mfma(Hs_Afrag, ff2_frag). B operands direct frag-major global (L2-hot).
__global__ __launch_bounds__(256) void ffn_kernel(
    const ushort* __restrict__ A,      // xnb (LN2 out), M x 256
    const ushort* __restrict__ W1t,    // ff1 frag-major, NT=64
    const ushort* __restrict__ W2t,    // ff2 frag-major, NT=16, K=1024
    const float* __restrict__ b1, const float* __restrict__ b2,
    const ushort* __restrict__ x1b,    // resid bf16
    float* __restrict__ out) {
    __shared__ ushort As[16 * 256];
    __shared__ ushort Hs[2048];        // 16 x 128 bf16, group-major
    const int tid = threadIdx.x;
    const int lane = tid & 63, wid = tid >> 6;
    const int l15 = lane & 15, hi = lane >> 4;
    const int row0 = blockIdx.x * 16;

    #pragma unroll
    for (int t = 0; t < 2; t++) {
        int c = tid + t * 256;
        int r = c >> 5, cb = (c & 31) * 16;
        short8 va = *(const short8*)(A + (size_t)(row0 + r) * 256 + (c & 31) * 8);
        *(short8*)((char*)As + r * 512 + (cb ^ ((r & 7) << 4))) = va;
    }
    __syncthreads();

    f32x4 acc[4];
    #pragma unroll
    for (int n = 0; n < 4; n++) acc[n] = (f32x4){0.f, 0.f, 0.f, 0.f};

    const int hwr = (4 * wid + (hi >> 1)) * 256 + l15 * 16 + (hi & 1) * 8;  // Hs write base (bytes)

    for (int ch = 0; ch < 8; ch++) {
        // FF1 chunk: wave computes h[16 rows][wid*32 .. +31]
        f32x4 hacc[2];
        hacc[0] = (f32x4){0.f, 0.f, 0.f, 0.f};
        hacc[1] = (f32x4){0.f, 0.f, 0.f, 0.f};
        #pragma unroll
        for (int tk = 0; tk < 8; tk++) {
            short8 xb = *(const short8*)((char*)As + l15 * 512 + ((tk * 64 + hi * 16) ^ ((l15 & 7) << 4)));
            #pragma unroll
            for (int nf = 0; nf < 2; nf++) {
                int tnf = ch * 8 + wid * 2 + nf;
                short8 fa = *(const short8*)(W1t + (((size_t)tk * 64 + tnf) << 9) + lane * 8);
                hacc[nf] = __builtin_amdgcn_mfma_f32_16x16x32_bf16(fa, xb, hacc[nf], 0, 0, 0);
            }
        }
        __syncthreads();  // previous chunk's Hs fully consumed
        // bias + GELU + pack -> Hs (row q = l15, ffcol = wid*32 + nf*16 + hi*4 + r)
        #pragma unroll
        for (int nf = 0; nf < 2; nf++) {
            int fcb = ch * 128 + wid * 32 + nf * 16 + hi * 4;
            float g[4];
            #pragma unroll
            for (int r = 0; r < 4; r++) {
                float v = hacc[nf][r] + b1[fcb + r];
                g[r] = 0.5f * v * (1.f + erff(v * 0.70710678118654752f));
            }
            unsigned lo  = cvtpk(g[0], g[1]);
            unsigned hi2 = cvtpk(g[2], g[3]);
            *(unsigned long long*)((char*)Hs + (nf << 9) + hwr) =
                ((unsigned long long)hi2 << 32) | (unsigned long long)lo;
        }
        __syncthreads();  // Hs visible to all waves
        // FF2 accumulate: out[16][wid*64..+63] += Hs @ ff2_chunk^T
        #pragma unroll
        for (int s = 0; s < 4; s++) {
            short8 pa = *(const short8*)((char*)Hs + (4 * s + hi) * 256 + l15 * 16);
            int tk2 = ch * 4 + s;
            #pragma unroll
            for (int n = 0; n < 4; n++) {
                short8 bfr = *(const short8*)(W2t + (((size_t)tk2 * 16 + wid * 4 + n) << 9) + lane * 8);
                acc[n] = __builtin_amdgcn_mfma_f32_16x16x32_bf16(pa, bfr, acc[n], 0, 0, 0);
            }
        }
    }

    #pragma unroll
    for (int n = 0; n < 4; n++) {
        #pragma unroll
        for (int r = 0; r < 4; r++) {
            size_t row = row0 + hi * 4 + r;
            int col = wid * 64 + n * 16 + l15;
            float rv = bf2f(x1b[row * 256 + col]);
            out[row * 256 + col] = acc[n][r] + b2[col] + rv;
        }
    }
}

// ---------------- MFMA flash attention: banded, independent waves, reg prefetch -----
__global__ __launch_bounds__(256) void attn_mfma(
    const ushort* __restrict__ qb, const ushort* __restrict__ kb,
    const ushort* __restrict__ vt, const float* __restrict__ slopes,
    ushort* __restrict__ ctxout) {
    __shared__ ushort plds[4][1024];
    const int tid = threadIdx.x;
    const int wid = tid >> 6, lane = tid & 63;
    const int l15 = lane & 15, hi = lane >> 4;
    const int bh = blockIdx.y, h = bh & (N_HEADS - 1), bb = bh >> 3;
    const int qt = blockIdx.x * 4 + wid;
    const int qbase = qt * 16;
    const float slope = fabsf(slopes[h]) * 1.4426950408889634f;  // log2 units

    const int wl = (int)fminf(2048.f, 32.f / fmaxf(slope, 1e-6f));
    const int tlo = max(0, (qbase - wl) >> 6);
    const int thi = min(31, (qbase + 15 + wl) >> 6);

    const ushort* Kg = kb + (size_t)bh * 32 * 2048;
    const ushort* Vg = vt + (size_t)bh * 32 * 2048;

    short8 qf = *(const short8*)(qb + ((size_t)bh * S_LEN + qbase + l15) * HEAD_DIM + hi * 8);

    f32x4 ctxa[2];
    ctxa[0] = (f32x4){0.f, 0.f, 0.f, 0.f};
    ctxa[1] = (f32x4){0.f, 0.f, 0.f, 0.f};
    float lsum = 0.f;

    char* pw = (char*)&plds[wid][0];
    const int bpi = lane & 0x30;
    const int wr_off = ((hi >> 1) << 8) + (l15 << 4) + ((hi & 1) << 3);
    const int rd0 = (hi << 8) + (l15 << 4);

    const float qoff = (float)(qbase + l15 - 4 * hi);

    short8 kfc[4], vfc[2][2];
    {
        const ushort* Kt = Kg + (size_t)tlo * 2048;
        const ushort* Vt = Vg + (size_t)tlo * 2048;
        #pragma unroll
        for (int c = 0; c < 4; c++)
            kfc[c] = *(const short8*)(Kt + (hi * 64 + 16 * c + l15) * 8);
        #pragma unroll
        for (int f = 0; f < 2; f++)
            #pragma unroll
            for (int dt = 0; dt < 2; dt++)
                vfc[f][dt] = *(const short8*)(Vt + ((f * 4 + hi) * 32 + dt * 16 + l15) * 8);
    }

    for (int t = tlo; t <= thi; ++t) {
        short8 kfn[4], vfn[2][2];
        if (t < thi) {
            const ushort* Kt = Kg + (size_t)(t + 1) * 2048;
            const ushort* Vt = Vg + (size_t)(t + 1) * 2048;
            #pragma unroll
            for (int c = 0; c < 4; c++)
                kfn[c] = *(const short8*)(Kt + (hi * 64 + 16 * c + l15) * 8);
            #pragma unroll
            for (int f = 0; f < 2; f++)
                #pragma unroll
                for (int dt = 0; dt < 2; dt++)
                    vfn[f][dt] = *(const short8*)(Vt + ((f * 4 + hi) * 32 + dt * 16 + l15) * 8);
        }

        const f32x4 z = {0.f, 0.f, 0.f, 0.f};
        f32x4 s[4];
        __builtin_amdgcn_s_setprio(1);
        #pragma unroll
        for (int c = 0; c < 4; c++)
            s[c] = __builtin_amdgcn_mfma_f32_16x16x32_bf16(kfc[c], qf, z, 0, 0, 0);
        __builtin_amdgcn_s_setprio(0);

        float dkt = qoff - (float)(64 * t);
        #pragma unroll
        for (int c = 0; c < 4; c++) {
            float d0 = dkt - (float)(16 * c);
            #pragma unroll
            for (int r = 0; r < 4; r++)
                s[c][r] = exp2f(fmaf(-slope, fabsf(d0 - (float)r), s[c][r]));
        }
        f32x4 t01 = s[0] + s[1], t23 = s[2] + s[3];
        f32x4 tt = t01 + t23;
        float tsum = (tt[0] + tt[1]) + (tt[2] + tt[3]);
        tsum += __shfl_xor(tsum, 16);
        tsum += __shfl_xor(tsum, 32);
        lsum += tsum;

        #pragma unroll
        for (int c = 0; c < 4; c++) {
            unsigned lo  = cvtpk(s[c][0], s[c][1]);
            unsigned hi2 = cvtpk(s[c][2], s[c][3]);
            *(unsigned long long*)(pw + (c << 9) + wr_off) =
                ((unsigned long long)hi2 << 32) | (unsigned long long)lo;
        }
        asm volatile("s_waitcnt lgkmcnt(0)" ::: "memory");
        short8 pa0 = *(const short8*)(pw + rd0);
        short8 pa1 = *(const short8*)(pw + 1024 + rd0);
        __builtin_amdgcn_s_setprio(1);
        #pragma unroll
        for (int dt = 0; dt < 2; dt++) {
            ctxa[dt] = __builtin_amdgcn_mfma_f32_16x16x32_bf16(pa0, vfc[0][dt], ctxa[dt], 0, 0, 0);
            ctxa[dt] = __builtin_amdgcn_mfma_f32_16x16x32_bf16(pa1, vfc[1][dt], ctxa[dt], 0, 0, 0);
        }
        __builtin_amdgcn_s_setprio(0);

        #pragma unroll
        for (int c = 0; c < 4; c++) kfc[c] = kfn[c];
        #pragma unroll
        for (int f = 0; f < 2; f++)
            #pragma unroll
            for (int dt = 0; dt < 2; dt++) vfc[f][dt] = vfn[f][dt];
    }
    float inv = 1.f / lsum;
    int invi = __builtin_bit_cast(int, inv);
    #pragma unroll
    for (int r = 0; r < 4; r++) {
        float ir = __builtin_bit_cast(float, __builtin_amdgcn_ds_bpermute(bpi + 4 * r, invi));
        size_t row = (size_t)bb * S_LEN + qbase + 4 * hi + r;
        #pragma unroll
        for (int dt = 0; dt < 2; dt++)
            ctxout[row * D_MODEL + h * HEAD_DIM + dt * 16 + l15] = f2bf(ctxa[dt][r] * ir);
    }
}

// ---------------- launcher ----------------
extern "C" void kernel_launch(void* const* d_in, const int* in_sizes, int n_in,
                              void* d_out, int out_size, void* d_ws, size_t ws_size,
                              hipStream_t stream) {
    const float* x      = (const float*)d_in[0];
    const float* in_w   = (const float*)d_in[1];
    const float* in_b   = (const float*)d_in[2];
    const float* outw   = (const float*)d_in[3];
    const float* outb   = (const float*)d_in[4];
    const float* ln1w   = (const float*)d_in[5];
    const float* ln1b   = (const float*)d_in[6];
    const float* ln2w   = (const float*)d_in[7];
    const float* ln2b   = (const float*)d_in[8];
    const float* ff1w   = (const float*)d_in[9];
    const float* ff1b   = (const float*)d_in[10];
    const float* ff2w   = (const float*)d_in[11];
    const float* ff2b   = (const float*)d_in[12];
    const float* slopes = (const float*)d_in[13];
    float* out = (float*)d_out;

    const size_t SZ = (size_t)ROWS_TOTAL * D_MODEL;  // 2,097,152 elements
    ushort* xnb   = (ushort*)d_ws;          // 4MB (LN1 out, reused for LN2 out)
    ushort* ctxb  = xnb + SZ;               // 4MB
    ushort* qb16  = ctxb + SZ;              // 4MB
    ushort* kb16  = qb16 + SZ;              // 4MB (frag-major tiled)
    ushort* vt16  = kb16 + SZ;              // 4MB (frag-major tiled)
    ushort* x1b   = vt16 + SZ;              // 4MB bf16 (x + attn_out)
    ushort* wqkvt = x1b + SZ;               // 768x256 frag-major
    ushort* woutt = wqkvt + 768 * 256;      // 256x256
    ushort* wff1t = woutt + 256 * 256;      // 1024x256
    ushort* wff2t = wff1t + 1024 * 256;     // 256x1024

    // 0. weights -> frag-major bf16  +  LN1 -> bf16
    prep_kernel<<<768 + ROWS_TOTAL / 4, 256, 0, stream>>>(
        in_w, outw, ff1w, ff2w, wqkvt, woutt, wff1t, wff2t, x, ln1w, ln1b, xnb);
    // 1. QKV projection + scatter (tiled K/V): grid 768
    gemm_qkv<<<dim3(ROWS_TOTAL / 64, 6), 256, 0, stream>>>(
        xnb, wqkvt, in_b, qb16, kb16, vt16);
    // 2. MFMA attention -> bf16 ctx
    attn_mfma<<<dim3(32, 32), 256, 0, stream>>>(qb16, kb16, vt16, slopes, ctxb);
    // 3. out proj + residual + LN2 fused: grid 512
    gemm_opln<<<ROWS_TOTAL / 16, 256, 0, stream>>>(
        ctxb, woutt, outb, x, ln2w, ln2b, xnb, x1b);
    // 4. fused FFN -> out: grid 512
    ffn_kernel<<<ROWS_TOTAL / 16, 256, 0, stream>>>(
        xnb, wff1t, wff2t, ff1b, ff2b, x1b, out);
}